// Round 6
// baseline (221.711 us; speedup 1.0000x reference)
//
#include <hip/hip_runtime.h>

// ConvByMoveLayer: out[b,f,o] = sum_m sum_c x[b, mask[m,f], c] * W[m,c,o] + bias[f,o]
// B=128, F=4096, C=32, O=32, M=9.
//
// Round 11: r10 two-pass + TRUE XCD affinity via HW_REG_XCC_ID work queues.
//   Evidence r6-r10: every gather structure converges to logical-bytes/9TB/s
//   = Infinity Cache rate; the blk%8->XCD round-robin assumption never gave
//   L2 residency. Now each pass2 block reads its REAL XCC id (hwreg 20, m09)
//   and pulls work (chunks of 2 field-tiles, phase-major) from its own XCD's
//   atomic queue in ws -> all gathers from a CU target the 1MB fp16 slice its
//   own XCD L2 serves, by construction. Chunks are claimed via atomicExch on
//   done[] (no double execution); a global steal loop after the home queue
//   guarantees full coverage even if XCC_ID were garbage (degrades to r10
//   perf, stays correct). pass1 and the pass2 tile body are bit-identical to
//   r10 (proven): permuted layout xh[f][b_hi][k][h][b_lo][j] makes one
//   halfx8 gather = one MFMA A-fragment, 8 lanes = one full 128B line.

#define B_ 128
#define F_ 4096
#define C_ 32
#define O_ 32
#define M_ 9
#define T_ 18              // K=16 MFMA slices (M_*C_/16)
#define CHUNKS_PER_XCD 256 // 4 phases x 64 chunks (chunk = 2 field tiles)
#define CHUNKS_TOTAL 2048

typedef _Float16 halfx4 __attribute__((ext_vector_type(4)));
typedef _Float16 halfx8 __attribute__((ext_vector_type(8)));
typedef float floatx4 __attribute__((ext_vector_type(4)));
typedef float floatx16 __attribute__((ext_vector_type(16)));

// ---------------- Pass 1: fp32 x[b][f][c] -> fp16 xh (permuted) ----------------
// pos_halves(f,b,c) = f*4096 + (b>>2)*128 + ((c>>4)*8 + ((c>>3)&1)*4 + (b&3))*8 + (c&7)
__global__ __launch_bounds__(256) void pass1_cvt(
    const float* __restrict__ x, _Float16* __restrict__ xh)
{
    const int blk = blockIdx.x;
    const int xcd = blk & 7;
    const int ft  = (blk >> 3) & 127;
    const int p   = blk >> 10;
    const int b0  = (p * 8 + xcd) * 4;
    const int f0  = ft * 32;
    const int fl  = threadIdx.x >> 3;    // field 0..31
    const int c4  = (threadIdx.x & 7) * 4;
    const int k   = c4 >> 4;
    const int h   = (c4 >> 3) & 1;
    const int j0  = c4 & 7;
    _Float16* dst = xh + (size_t)(f0 + fl) * (B_ * C_) + (b0 >> 2) * 128
                    + (k * 8 + h * 4) * 8 + j0;
#pragma unroll
    for (int q = 0; q < 4; ++q) {        // q = b_lo
        const floatx4 v = __builtin_nontemporal_load(
            reinterpret_cast<const floatx4*>(
                x + ((size_t)(b0 + q) * F_ + f0 + fl) * C_ + c4));
        halfx4 hv;
#pragma unroll
        for (int jj = 0; jj < 4; ++jj) hv[jj] = (_Float16)v[jj];
        *reinterpret_cast<halfx4*>(dst + q * 8) = hv;
    }
}

// ---------------- Pass 2 tile body (identical math to r10) ----------------
__device__ __forceinline__ void process_tile(
    const _Float16* __restrict__ xh, const int* __restrict__ mask,
    const float* __restrict__ biases, float* __restrict__ out,
    const _Float16* sw, int b0, int f0,
    int wave, int lane, int h, int fi, int bp, int o)
{
    const int fw = f0 + wave * 8;
    const int f  = fw + fi;

    int sidx[M_];
#pragma unroll
    for (int m = 0; m < M_; ++m) sidx[m] = mask[m * F_ + f];

    const _Float16* xb = xh + (b0 >> 2) * 128 + (h * 4 + bp) * 8;

    halfx8 a[T_];
#pragma unroll
    for (int m = 0; m < M_; ++m) {
        const _Float16* rp = xb + (size_t)sidx[m] * (B_ * C_);
        a[2 * m]     = *reinterpret_cast<const halfx8*>(rp);        // k=0
        a[2 * m + 1] = *reinterpret_cast<const halfx8*>(rp + 64);   // k=1
    }

    floatx16 acc;
#pragma unroll
    for (int i = 0; i < 16; ++i) acc[i] = 0.0f;
#pragma unroll
    for (int t = 0; t < T_; ++t) {
        const halfx8 bwt = *reinterpret_cast<const halfx8*>(&sw[(t * 64 + lane) * 8]);
        acc = __builtin_amdgcn_mfma_f32_32x32x16_f16(a[t], bwt, acc, 0, 0, 0);
    }

    float bv[4];
#pragma unroll
    for (int q = 0; q < 4; ++q)
        bv[q] = biases[(size_t)(fw + 2 * q + h) * O_ + o];

    // C/D layout (m74/m101): col = lane&31, orow = (r&3) + 8*(r>>2) + 4*h
#pragma unroll
    for (int r = 0; r < 16; ++r) {
        const int q   = r >> 2;
        const int obp = r & 3;
        const float v = acc[r] + bv[q];
        __builtin_nontemporal_store(
            v, &out[((size_t)(b0 + obp) * F_ + fw + 2 * q + h) * O_ + o]);
    }
}

// ---------------- Pass 2: XCD-affine work-queue gather + MFMA ----------------
__global__ __launch_bounds__(256, 3) void pass2_gemm(
    const _Float16* __restrict__ xh, const int* __restrict__ mask,
    const float* __restrict__ coeffs, const float* __restrict__ biases,
    float* __restrict__ out, int* __restrict__ qctr, int* __restrict__ done)
{
    __shared__ _Float16 sw[T_ * 64 * 8];   // 18 KB B-fragments
    __shared__ int s_msg;
    const int tid = threadIdx.x;

    // sw[t][lane][j] = W[m=t>>1][c = 16*(t&1) + 8*(lane>>5) + j][o = lane&31]
    for (int id = tid; id < T_ * 64; id += 256) {
        const int t  = id >> 6;
        const int L  = id & 63;
        const int m  = t >> 1;
        const int cb = 16 * (t & 1) + 8 * (L >> 5);
        const int oo = L & 31;
        halfx8 w;
#pragma unroll
        for (int jj = 0; jj < 8; ++jj)
            w[jj] = (_Float16)coeffs[(m * C_ + cb + jj) * O_ + oo];
        *reinterpret_cast<halfx8*>(&sw[id * 8]) = w;
    }

    const int wave = tid >> 6;
    const int lane = tid & 63;
    const int h    = lane >> 5;
    const int row  = lane & 31;
    const int fi   = row >> 2;
    const int bp   = row & 3;
    const int o    = lane & 31;

    // Real XCD id (m09: hwreg 20 = HW_REG_XCC_ID). simm16 = 20 | (31<<11).
    int xcc;
    asm volatile("s_getreg_b32 %0, 0xf814" : "=s"(xcc));
    xcc &= 7;

    // ---- home loop: phase-major chunks from THIS XCD's queue ----
    for (;;) {
        __syncthreads();
        if (tid == 0) s_msg = atomicAdd(&qctr[xcc], 1);
        __syncthreads();
        const int c = s_msg;
        if (c >= CHUNKS_PER_XCD) break;
        __syncthreads();
        if (tid == 0) s_msg = atomicExch(&done[xcc * CHUNKS_PER_XCD + c], 1);
        __syncthreads();
        if (s_msg) continue;
        const int phase = c >> 6;
        const int ft0   = (c & 63) * 2;
        const int b0    = (phase * 8 + xcc) * 4;
        process_tile(xh, mask, biases, out, sw, b0, ft0 * 32,
                     wave, lane, h, fi, bp, o);
        process_tile(xh, mask, biases, out, sw, b0, (ft0 + 1) * 32,
                     wave, lane, h, fi, bp, o);
    }

    // ---- steal/cleanup loop: guarantees full coverage regardless of xcc ----
    for (;;) {
        __syncthreads();
        if (tid == 0) s_msg = atomicAdd(&qctr[8], 1);
        __syncthreads();
        const int g = s_msg;
        if (g >= CHUNKS_TOTAL) break;
        __syncthreads();
        if (tid == 0) s_msg = atomicExch(&done[g], 1);
        __syncthreads();
        if (s_msg) continue;
        const int xv    = g >> 8;            // owner XCD of this chunk
        const int c     = g & (CHUNKS_PER_XCD - 1);
        const int phase = c >> 6;
        const int ft0   = (c & 63) * 2;
        const int b0    = (phase * 8 + xv) * 4;
        process_tile(xh, mask, biases, out, sw, b0, ft0 * 32,
                     wave, lane, h, fi, bp, o);
        process_tile(xh, mask, biases, out, sw, b0, (ft0 + 1) * 32,
                     wave, lane, h, fi, bp, o);
    }
}

// ---------------- Fallback (correct, slow) if ws too small ----------------
__global__ __launch_bounds__(256) void fallback_kernel(
    const float* __restrict__ x, const int* __restrict__ mask,
    const float* __restrict__ coeffs, const float* __restrict__ biases,
    float* __restrict__ out)
{
    int gid = blockIdx.x * 256 + threadIdx.x;   // over B*F*O
    int o = gid & (O_ - 1);
    int f = (gid >> 5) & (F_ - 1);
    int b = gid >> 17;
    float acc = biases[f * O_ + o];
    for (int m = 0; m < M_; ++m) {
        int s = mask[m * F_ + f];
        const float* xr = x + ((size_t)b * F_ + s) * C_;
        const float* wr = coeffs + (m * C_) * O_ + o;
#pragma unroll
        for (int c = 0; c < C_; ++c)
            acc += xr[c] * wr[c * O_];
    }
    out[gid] = acc;
}

extern "C" void kernel_launch(void* const* d_in, const int* in_sizes, int n_in,
                              void* d_out, int out_size, void* d_ws, size_t ws_size,
                              hipStream_t stream) {
    const float* x      = (const float*)d_in[0];
    const int*   mask   = (const int*)d_in[1];
    const float* coeffs = (const float*)d_in[2];
    const float* biases = (const float*)d_in[3];
    float* out = (float*)d_out;

    const size_t xh_bytes  = (size_t)F_ * B_ * C_ * sizeof(_Float16);   // 32 MB
    const size_t ctl_bytes = (16 + CHUNKS_TOTAL) * sizeof(int);
    if (ws_size >= xh_bytes + ctl_bytes) {
        _Float16* xh = (_Float16*)d_ws;
        int* ctl = (int*)((char*)d_ws + xh_bytes);   // [0..7] XCD queues, [8] steal, [16..] done
        hipMemsetAsync(ctl, 0, ctl_bytes, stream);
        pass1_cvt<<<4096, 256, 0, stream>>>(x, xh);
        pass2_gemm<<<CHUNKS_TOTAL, 256, 0, stream>>>(
            xh, mask, coeffs, biases, out, ctl, ctl + 16);
    } else {
        fallback_kernel<<<(B_ * F_ * O_) / 256, 256, 0, stream>>>(
            x, mask, coeffs, biases, out);
    }
}

// Round 8
// 169.978 us; speedup vs baseline: 1.3043x; 1.3043x over previous
//
#include <hip/hip_runtime.h>

// ConvByMoveLayer: out[b,f,o] = sum_m sum_c x[b, mask[m,f], c] * W[m,c,o] + bias[f,o]
// B=128, F=4096, C=32, O=32, M=9.
//
// Round 13: re-run of round 12 (bench infra failed twice; no kernel defect
// found on audit: queue loop is bounded, barriers uniform, memsetAsync is
// capture-legal and ran in r11, s_getreg path ran in r11).
//
// Round 12 design: XCD-affine gather, zero-overhead scheduler.
//   r11 proved the xcc-id work-queue mechanism correct but its steal loop
//   serialized ~4-6k same-address atomics (pass2 101us, VALUBusy 3%). Now:
//   8 padded per-XCD ticket counters (256B apart); each block drains queue
//   (xcc+sweep)&7 for sweep=0..7. Chunk claims are unique by construction
//   (only a queue's own atomicAdd hands out its chunks) -> no done[], no
//   atomicExch, no global steal counter. Coverage is sweep-guaranteed, so
//   correctness is independent of the xcc value; affinity is purely a
//   performance preference. tid0 volatile pre-check skips the atomic on
//   drained queues -> ~1 atomic + 2 barriers per chunk, 8 loads per block
//   at exit. Chunks are phase-major, phase-REVERSED (pass1 writes phases
//   ascending; reverse order hits the warmest L2 slices first).
//   pass1 + tile body verbatim from r10/r11 (passing, absmax 3.9e-3):
//   permuted fp16 layout xh[f][b_hi][k][h][b_lo][j] makes one halfx8 gather
//   = one MFMA A-fragment; 8 lanes of a field = one full 128B line.

#define B_ 128
#define F_ 4096
#define C_ 32
#define O_ 32
#define M_ 9
#define T_ 18              // K=16 MFMA slices (M_*C_/16)
#define CHUNKS_PER_XCD 256 // 4 phases x 64 chunks (chunk = 2 field tiles)
#define QSTRIDE 64         // ints between queue counters (256B padding)

typedef _Float16 halfx4 __attribute__((ext_vector_type(4)));
typedef _Float16 halfx8 __attribute__((ext_vector_type(8)));
typedef float floatx4 __attribute__((ext_vector_type(4)));
typedef float floatx16 __attribute__((ext_vector_type(16)));

// ---------------- Pass 1: fp32 x[b][f][c] -> fp16 xh (permuted) ----------------
// pos_halves(f,b,c) = f*4096 + (b>>2)*128 + ((c>>4)*8 + ((c>>3)&1)*4 + (b&3))*8 + (c&7)
__global__ __launch_bounds__(256) void pass1_cvt(
    const float* __restrict__ x, _Float16* __restrict__ xh)
{
    const int blk = blockIdx.x;
    const int xcd = blk & 7;
    const int ft  = (blk >> 3) & 127;
    const int p   = blk >> 10;
    const int b0  = (p * 8 + xcd) * 4;
    const int f0  = ft * 32;
    const int fl  = threadIdx.x >> 3;    // field 0..31
    const int c4  = (threadIdx.x & 7) * 4;
    const int k   = c4 >> 4;
    const int h   = (c4 >> 3) & 1;
    const int j0  = c4 & 7;
    _Float16* dst = xh + (size_t)(f0 + fl) * (B_ * C_) + (b0 >> 2) * 128
                    + (k * 8 + h * 4) * 8 + j0;
#pragma unroll
    for (int q = 0; q < 4; ++q) {        // q = b_lo
        const floatx4 v = __builtin_nontemporal_load(
            reinterpret_cast<const floatx4*>(
                x + ((size_t)(b0 + q) * F_ + f0 + fl) * C_ + c4));
        halfx4 hv;
#pragma unroll
        for (int jj = 0; jj < 4; ++jj) hv[jj] = (_Float16)v[jj];
        *reinterpret_cast<halfx4*>(dst + q * 8) = hv;
    }
}

// ---------------- Pass 2 tile body (verbatim r10/r11, proven) ----------------
__device__ __forceinline__ void process_tile(
    const _Float16* __restrict__ xh, const int* __restrict__ mask,
    const float* __restrict__ biases, float* __restrict__ out,
    const _Float16* sw, int b0, int f0,
    int wave, int lane, int h, int fi, int bp, int o)
{
    const int fw = f0 + wave * 8;
    const int f  = fw + fi;

    int sidx[M_];
#pragma unroll
    for (int m = 0; m < M_; ++m) sidx[m] = mask[m * F_ + f];

    const _Float16* xb = xh + (b0 >> 2) * 128 + (h * 4 + bp) * 8;

    halfx8 a[T_];
#pragma unroll
    for (int m = 0; m < M_; ++m) {
        const _Float16* rp = xb + (size_t)sidx[m] * (B_ * C_);
        a[2 * m]     = *reinterpret_cast<const halfx8*>(rp);        // k=0
        a[2 * m + 1] = *reinterpret_cast<const halfx8*>(rp + 64);   // k=1
    }

    floatx16 acc;
#pragma unroll
    for (int i = 0; i < 16; ++i) acc[i] = 0.0f;
#pragma unroll
    for (int t = 0; t < T_; ++t) {
        const halfx8 bwt = *reinterpret_cast<const halfx8*>(&sw[(t * 64 + lane) * 8]);
        acc = __builtin_amdgcn_mfma_f32_32x32x16_f16(a[t], bwt, acc, 0, 0, 0);
    }

    float bv[4];
#pragma unroll
    for (int q = 0; q < 4; ++q)
        bv[q] = biases[(size_t)(fw + 2 * q + h) * O_ + o];

    // C/D layout (m74/m101): col = lane&31, orow = (r&3) + 8*(r>>2) + 4*h
#pragma unroll
    for (int r = 0; r < 16; ++r) {
        const int q   = r >> 2;
        const int obp = r & 3;
        const float v = acc[r] + bv[q];
        __builtin_nontemporal_store(
            v, &out[((size_t)(b0 + obp) * F_ + fw + 2 * q + h) * O_ + o]);
    }
}

// ---------------- Pass 2: XCD-affine ticket queues + MFMA ----------------
__global__ __launch_bounds__(256, 3) void pass2_gemm(
    const _Float16* __restrict__ xh, const int* __restrict__ mask,
    const float* __restrict__ coeffs, const float* __restrict__ biases,
    float* __restrict__ out, int* __restrict__ qctr)
{
    __shared__ _Float16 sw[T_ * 64 * 8];   // 18 KB B-fragments
    __shared__ int s_msg;
    const int tid = threadIdx.x;

    // sw[t][lane][j] = W[m=t>>1][c = 16*(t&1) + 8*(lane>>5) + j][o = lane&31]
    for (int id = tid; id < T_ * 64; id += 256) {
        const int t  = id >> 6;
        const int L  = id & 63;
        const int m  = t >> 1;
        const int cb = 16 * (t & 1) + 8 * (L >> 5);
        const int oo = L & 31;
        halfx8 w;
#pragma unroll
        for (int jj = 0; jj < 8; ++jj)
            w[jj] = (_Float16)coeffs[(m * C_ + cb + jj) * O_ + oo];
        *reinterpret_cast<halfx8*>(&sw[id * 8]) = w;
    }

    const int wave = tid >> 6;
    const int lane = tid & 63;
    const int h    = lane >> 5;
    const int row  = lane & 31;
    const int fi   = row >> 2;
    const int bp   = row & 3;
    const int o    = lane & 31;

    // Real XCD id (m09: hwreg 20 = HW_REG_XCC_ID). simm16 = 20 | (31<<11).
    int xcc;
    asm volatile("s_getreg_b32 %0, 0xf814" : "=s"(xcc));
    xcc &= 7;

    // Drain own XCD's queue first, then sweep the rest (coverage guarantee;
    // claims unique because only a queue's own atomicAdd assigns its chunks).
    for (int sweep = 0; sweep < 8; ++sweep) {
        const int qid = (xcc + sweep) & 7;
        int* qp = &qctr[qid * QSTRIDE];
        for (;;) {
            __syncthreads();             // protects s_msg (incl. sw-build wait)
            if (tid == 0) {
                int v = *(volatile int*)qp;
                s_msg = (v >= CHUNKS_PER_XCD) ? 0x7fffffff : atomicAdd(qp, 1);
            }
            __syncthreads();
            const int c = s_msg;
            if (c >= CHUNKS_PER_XCD) break;
            const int phase = 3 - (c >> 6);        // reversed: warm slices first
            const int ft0   = (c & 63) * 2;
            const int b0    = (phase * 8 + qid) * 4;
            process_tile(xh, mask, biases, out, sw, b0, ft0 * 32,
                         wave, lane, h, fi, bp, o);
            process_tile(xh, mask, biases, out, sw, b0, (ft0 + 1) * 32,
                         wave, lane, h, fi, bp, o);
        }
    }
}

// ---------------- Fallback (correct, slow) if ws too small ----------------
__global__ __launch_bounds__(256) void fallback_kernel(
    const float* __restrict__ x, const int* __restrict__ mask,
    const float* __restrict__ coeffs, const float* __restrict__ biases,
    float* __restrict__ out)
{
    int gid = blockIdx.x * 256 + threadIdx.x;   // over B*F*O
    int o = gid & (O_ - 1);
    int f = (gid >> 5) & (F_ - 1);
    int b = gid >> 17;
    float acc = biases[f * O_ + o];
    for (int m = 0; m < M_; ++m) {
        int s = mask[m * F_ + f];
        const float* xr = x + ((size_t)b * F_ + s) * C_;
        const float* wr = coeffs + (m * C_) * O_ + o;
#pragma unroll
        for (int c = 0; c < C_; ++c)
            acc += xr[c] * wr[c * O_];
    }
    out[gid] = acc;
}

extern "C" void kernel_launch(void* const* d_in, const int* in_sizes, int n_in,
                              void* d_out, int out_size, void* d_ws, size_t ws_size,
                              hipStream_t stream) {
    const float* x      = (const float*)d_in[0];
    const int*   mask   = (const int*)d_in[1];
    const float* coeffs = (const float*)d_in[2];
    const float* biases = (const float*)d_in[3];
    float* out = (float*)d_out;

    const size_t xh_bytes  = (size_t)F_ * B_ * C_ * sizeof(_Float16);   // 32 MB
    const size_t ctl_bytes = 8 * QSTRIDE * sizeof(int);                 // 2 KB
    if (ws_size >= xh_bytes + ctl_bytes) {
        _Float16* xh = (_Float16*)d_ws;
        int* ctl = (int*)((char*)d_ws + xh_bytes);   // 8 padded queue counters
        hipMemsetAsync(ctl, 0, ctl_bytes, stream);
        pass1_cvt<<<4096, 256, 0, stream>>>(x, xh);
        pass2_gemm<<<2048, 256, 0, stream>>>(xh, mask, coeffs, biases, out, ctl);
    } else {
        fallback_kernel<<<(B_ * F_ * O_) / 256, 256, 0, stream>>>(
            x, mask, coeffs, biases, out);
    }
}